// Round 1
// baseline (936.098 us; speedup 1.0000x reference)
//
#include <hip/hip_runtime.h>

// HSMM forward, restructured as scaled linear recurrence.
// ws layout (needs ~45.3 MiB):
//   H      : bf16 [16][512][11][256]  = 46,137,344 B  (emission*lterm, exp-domain, shift-aligned)
//   part   : f32  [11][88][256]       =    991,232 B  (sum-exp partials)
//   Pexp   : f32  [256][256]          =    262,144 B  (exp(log_softmax(z_per_z)))
//   logZ   : f32  [11][256]
//   lseZ   : f32  [256]
//   lt     : f32  [11][256]           (exp(l_term))
//   ltmz   : f32  [11][256]           (l_term - logZ)

#define VV 50000
#define ZB 256
#define LB 11
#define BB 16
#define TB 512
#define NCHUNK 88
#define CROWS 569  // ceil(VV/NCHUNK)

static __device__ __forceinline__ float bf16u_to_f(unsigned short u) {
  return __uint_as_float(((unsigned int)u) << 16);
}
static __device__ __forceinline__ unsigned short f_to_bf16u(float f) {
  unsigned int b = __float_as_uint(f);
  b += 0x7FFFu + ((b >> 16) & 1u);
  return (unsigned short)(b >> 16);
}

// ---- K1: per-chunk sum of exp(emb) over v (no-max: emb ~ N(0,1), safe in f32)
__global__ void k1_sumexp(const float* __restrict__ emb, float* __restrict__ part) {
  const int l = blockIdx.x / NCHUNK;
  const int c = blockIdx.x % NCHUNK;
  const int t = threadIdx.x;           // 512 threads
  const int zi = (t & 63) * 4;
  const int ro = t >> 6;               // 0..7
  const int v0 = c * CROWS;
  const int v1 = (v0 + CROWS < VV) ? (v0 + CROWS) : VV;
  const float* base = emb + (size_t)l * VV * ZB;
  float a0 = 0.f, a1 = 0.f, a2 = 0.f, a3 = 0.f;
  int v = v0 + ro;
  for (; v + 24 < v1; v += 32) {
    float4 x0 = *(const float4*)(base + (size_t)(v)*ZB + zi);
    float4 x1 = *(const float4*)(base + (size_t)(v + 8) * ZB + zi);
    float4 x2 = *(const float4*)(base + (size_t)(v + 16) * ZB + zi);
    float4 x3 = *(const float4*)(base + (size_t)(v + 24) * ZB + zi);
    a0 += __expf(x0.x) + __expf(x1.x) + __expf(x2.x) + __expf(x3.x);
    a1 += __expf(x0.y) + __expf(x1.y) + __expf(x2.y) + __expf(x3.y);
    a2 += __expf(x0.z) + __expf(x1.z) + __expf(x2.z) + __expf(x3.z);
    a3 += __expf(x0.w) + __expf(x1.w) + __expf(x2.w) + __expf(x3.w);
  }
  for (; v < v1; v += 8) {
    float4 x0 = *(const float4*)(base + (size_t)v * ZB + zi);
    a0 += __expf(x0.x); a1 += __expf(x0.y); a2 += __expf(x0.z); a3 += __expf(x0.w);
  }
  __shared__ float red[8][ZB];
  red[ro][zi] = a0; red[ro][zi + 1] = a1; red[ro][zi + 2] = a2; red[ro][zi + 3] = a3;
  __syncthreads();
  if (t < ZB) {
    float s = 0.f;
#pragma unroll
    for (int r = 0; r < 8; ++r) s += red[r][t];
    part[((size_t)l * NCHUNK + c) * ZB + t] = s;
  }
}

// ---- K2: combine partials -> logZ; lse over l of l_per_z; Pexp rows
__global__ void k2_combine(const float* __restrict__ part, const float* __restrict__ zpz,
                           const float* __restrict__ lpz, float* __restrict__ logZ,
                           float* __restrict__ lseZ, float* __restrict__ Pexp) {
  const int bid = blockIdx.x;
  const int t = threadIdx.x;  // 256
  if (bid < LB) {
    float s = 0.f;
    for (int c = 0; c < NCHUNK; ++c) s += part[((size_t)bid * NCHUNK + c) * ZB + t];
    logZ[bid * ZB + t] = __logf(s);
  } else if (bid == LB) {
    float lv[LB]; float m = -1e30f;
#pragma unroll
    for (int l = 0; l < LB; ++l) { lv[l] = lpz[t * LB + l]; m = fmaxf(m, lv[l]); }
    float s = 0.f;
#pragma unroll
    for (int l = 0; l < LB; ++l) s += __expf(lv[l] - m);
    lseZ[t] = m + __logf(s);
  } else {
    const int r = bid - (LB + 1);
    const float x = zpz[r * ZB + t];
    __shared__ float sA[4], sB[4];
    float m = x;
#pragma unroll
    for (int off = 32; off >= 1; off >>= 1) m = fmaxf(m, __shfl_xor(m, off, 64));
    if ((t & 63) == 0) sA[t >> 6] = m;
    __syncthreads();
    m = fmaxf(fmaxf(sA[0], sA[1]), fmaxf(sA[2], sA[3]));
    const float e = __expf(x - m);
    float s = e;
#pragma unroll
    for (int off = 32; off >= 1; off >>= 1) s += __shfl_xor(s, off, 64);
    if ((t & 63) == 0) sB[t >> 6] = s;
    __syncthreads();
    const float tot = sB[0] + sB[1] + sB[2] + sB[3];
    Pexp[r * ZB + t] = e / tot;
  }
}

// ---- K3: small tables lt = exp(l_term), ltmz = l_term - logZ
__global__ void k3_tables(const float* __restrict__ logZ, const float* __restrict__ lseZ,
                          const float* __restrict__ lpz, float* __restrict__ lt,
                          float* __restrict__ ltmz) {
  const int l = blockIdx.x; const int z = threadIdx.x;
  const float ll = lpz[z * LB + l] - lseZ[z];
  lt[l * ZB + z] = __expf(ll);
  ltmz[l * ZB + z] = ll - logZ[l * ZB + z];
}

// ---- K4: build shift-aligned exp-domain emissions H[b][n][l][z] (bf16)
__global__ void k4_build(const int* __restrict__ ng, const float* __restrict__ emb,
                         const float* __restrict__ lt, const float* __restrict__ ltmz,
                         unsigned short* __restrict__ H) {
  const int n = blockIdx.x + 1;
  const int b = blockIdx.y;
  const int z = threadIdx.x;  // 256
  unsigned short* hrow = H + ((size_t)b * TB + n) * LB * ZB + z;
#pragma unroll
  for (int l = 0; l < LB; ++l) {
    const int s = n - 1 - l;
    float h = 0.f;
    if (s >= 0) {
      const int id = ng[((size_t)l * BB + b) * TB + s];
      if (id == 0) h = lt[l * ZB + z];
      else if (id != 1) h = __expf(emb[((size_t)l * VV + id) * ZB + z] + ltmz[l * ZB + z]);
    }
    hrow[(size_t)l * ZB] = f_to_bf16u(h);
  }
}

// ---- K5: the scan. One workgroup (512 thr) per batch element.
__global__ __launch_bounds__(512, 2)
void k5_forward(const float* __restrict__ Pexp, const unsigned short* __restrict__ H,
                const int* __restrict__ xlen, float* __restrict__ out) {
  const int b = blockIdx.x;
  const int t = threadIdx.x;
  const int q = t >> 8;    // z-half for matvec
  const int j = t & 255;   // output column

  __shared__ float msgw[LB][ZB];               // scaled msg window (circular)
  __shared__ __align__(16) float S_lds[ZB];    // beta (exp-domain, scale C)
  __shared__ float partl[2][ZB];
  __shared__ float wmax[2][4];                 // stale-max cells (double-buffered)
  __shared__ float wsum[4];                    // deferred output sum
  __shared__ float red[ZB];

  // P half-column, register resident: Preg[zz] = P[q*128+zz][j]
  float Preg[128];
#pragma unroll
  for (int zz = 0; zz < 128; ++zz) Preg[zz] = Pexp[(q * 128 + zz) * ZB + j];

  // init: m0 = max_z P[0][z]
  if (t < ZB) red[t] = Pexp[t];
  __syncthreads();
  for (int sft = 128; sft >= 1; sft >>= 1) {
    if (t < sft) red[t] = fmaxf(red[t], red[t + sft]);
    __syncthreads();
  }
  const float m0 = red[0];

  const int xl = xlen[b];
  if (xl == 0 && t == 0) out[b] = 0.f;  // betas[0] = init -> LSE = 0

  float w[LB];                      // w[l] = exp(M_l - C)
  float C = 0.f, creg = 0.f, Sreg = 0.f;
  unsigned short hc[LB], hn[LB];
  int base = 0;

  if (t < ZB) {
    const float p0 = Pexp[t];       // msg0 = log_z[0,:] in exp domain
    msgw[0][t] = p0 / m0;
#pragma unroll
    for (int l = 1; l < LB; ++l) msgw[l][t] = 0.f;
    C = __logf(m0);
    w[0] = 1.f;
#pragma unroll
    for (int l = 1; l < LB; ++l) w[l] = 0.f;
    if (t < 4) { wmax[0][t] = 1.f; wmax[1][t] = 1.f; }
    const unsigned short* hp = H + ((size_t)b * TB + 1) * LB * ZB + t;
#pragma unroll
    for (int l = 0; l < LB; ++l) hc[l] = hp[l * ZB];
  }
  __syncthreads();

  for (int n = 1; n < TB; ++n) {
    // (A) S[z] = sum_l w_l * H_l[z] * msgx_l[z]   (threads 0..255) + prefetch H(n+1)
    if (t < ZB) {
      float s = 0.f;
#pragma unroll
      for (int l = 0; l < LB; ++l) {
        int sl = base + l; if (sl >= LB) sl -= LB;
        s = fmaf(w[l] * bf16u_to_f(hc[l]), msgw[sl][t], s);
      }
      S_lds[t] = s;
      Sreg = s;
      const int np = (n < TB - 1) ? n + 1 : n;
      const unsigned short* hp = H + ((size_t)b * TB + np) * LB * ZB + t;
#pragma unroll
      for (int l = 0; l < LB; ++l) hn[l] = hp[l * ZB];
    }
    __syncthreads();
    // (B) matvec half-dot: part[q][j] = sum_{z in half q} S[z]*P[z][j]
    {
      float acc = 0.f;
      const float4* Sv = (const float4*)(S_lds + q * 128);
#pragma unroll
      for (int c = 0; c < 32; ++c) {
        const float4 sv = Sv[c];
        acc = fmaf(sv.x, Preg[4 * c + 0], acc);
        acc = fmaf(sv.y, Preg[4 * c + 1], acc);
        acc = fmaf(sv.z, Preg[4 * c + 2], acc);
        acc = fmaf(sv.w, Preg[4 * c + 3], acc);
      }
      partl[q][j] = acc;
    }
    __syncthreads();
    // (C) combine, stale-max rescale, window push, scale bookkeeping
    if (t < ZB) {
      const float raw = partl[0][t] + partl[1][t];
      const int pr = (n - 1) & 1;
      float mx = fmaxf(fmaxf(wmax[pr][0], wmax[pr][1]), fmaxf(wmax[pr][2], wmax[pr][3]));
      mx = fmaxf(mx, 1e-35f);
      int nb = base - 1; if (nb < 0) nb = LB - 1;
      msgw[nb][t] = raw * (1.0f / mx);
      float wmv = raw;
#pragma unroll
      for (int off = 32; off >= 1; off >>= 1) wmv = fmaxf(wmv, __shfl_xor(wmv, off, 64));
      if ((t & 63) == 0) wmax[n & 1][t >> 6] = wmv;

      // deferred output write (wsum/creg captured at n == xl)
      if (xl > 0 && n == xl + 1 && t == 0)
        out[b] = __logf(wsum[0] + wsum[1] + wsum[2] + wsum[3]) + creg;
      if (n == xl) {
        creg = C;   // out = C_n + log(sum_z S_n)
        float sv = Sreg;
#pragma unroll
        for (int off = 32; off >= 1; off >>= 1) sv += __shfl_xor(sv, off, 64);
        if ((t & 63) == 0) wsum[t >> 6] = sv;
      }

      // C' = max(M_new, max old M[0..9]);  shift w's
      const float delta = __logf(mx);                 // M_new = C + delta
      float mw = w[0];
#pragma unroll
      for (int l = 1; l < LB - 1; ++l) mw = fmaxf(mw, w[l]);
      const float lg = __logf(fmaxf(mw, 1e-37f));
      const float a = fmaxf(delta, lg);
      const float es = __expf(-a);
#pragma unroll
      for (int l = LB - 1; l >= 1; --l) w[l] = w[l - 1] * es;
      w[0] = __expf(delta - a);
      C += a;
      base = nb;
#pragma unroll
      for (int l = 0; l < LB; ++l) hc[l] = hn[l];
    }
  }
}

extern "C" void kernel_launch(void* const* d_in, const int* in_sizes, int n_in,
                              void* d_out, int out_size, void* d_ws, size_t ws_size,
                              hipStream_t stream) {
  (void)in_sizes; (void)n_in; (void)out_size; (void)ws_size;
  const int* xlen = (const int*)d_in[1];
  const int* ng = (const int*)d_in[2];
  const float* emb = (const float*)d_in[3];
  const float* zpz = (const float*)d_in[4];
  const float* lpz = (const float*)d_in[5];
  float* out = (float*)d_out;

  char* ws = (char*)d_ws;
  unsigned short* H = (unsigned short*)ws;
  size_t off = (size_t)BB * TB * LB * ZB * 2;
  float* part = (float*)(ws + off); off += (size_t)LB * NCHUNK * ZB * 4;
  float* Pexp = (float*)(ws + off); off += (size_t)ZB * ZB * 4;
  float* logZ = (float*)(ws + off); off += (size_t)LB * ZB * 4;
  float* lseZ = (float*)(ws + off); off += (size_t)ZB * 4;
  float* lt = (float*)(ws + off); off += (size_t)LB * ZB * 4;
  float* ltmz = (float*)(ws + off); off += (size_t)LB * ZB * 4;

  k1_sumexp<<<dim3(LB * NCHUNK), dim3(512), 0, stream>>>(emb, part);
  k2_combine<<<dim3(LB + 1 + ZB), dim3(ZB), 0, stream>>>(part, zpz, lpz, logZ, lseZ, Pexp);
  k3_tables<<<dim3(LB), dim3(ZB), 0, stream>>>(logZ, lseZ, lpz, lt, ltmz);
  k4_build<<<dim3(TB - 1, BB), dim3(ZB), 0, stream>>>(ng, emb, lt, ltmz, H);
  k5_forward<<<dim3(BB), dim3(512), 0, stream>>>(Pexp, H, xlen, out);
}